// Round 8
// baseline (213.782 us; speedup 1.0000x reference)
//
#include <hip/hip_runtime.h>
#include <math.h>

#define NN 8192
#define CC 256
#define LOG2N 13

typedef float f32x4 __attribute__((ext_vector_type(4)));

// ---------------- ws layout ----------------
// floats: accZ[256] | accR[256] | accXH[256]        (atomicAdd accumulators)
// uints : ctr at uint-index 1024, done at uint-index 1056 (separate cache lines)
// All zeroed each call by one captured hipMemsetAsync (8 KB).
#define ACC_Z  0
#define ACC_R  256
#define ACC_XH 512

#define NAGG   128
#define NMV    20
#define CHAIN  (NAGG + NMV)       // 148
#define GRID   2048               // all resident at t=0 (8 blocks/CU @ 4 waves)
#define CHUNK  4096               // f32x4 per stolen chunk (64 KB read)
#define NCHUNK 4096               // 16,777,216 f32x4 / 4096

__global__ void __launch_bounds__(256) k1(
        const float* __restrict__ X, const float* __restrict__ E,
        const float* __restrict__ H,
        const int* __restrict__ dh, const int* __restrict__ dt,
        const float* __restrict__ Wxz, const float* __restrict__ Whz,
        const float* __restrict__ Cz,  const float* __restrict__ Wxr,
        const float* __restrict__ Whr, const float* __restrict__ Cr,
        const float* __restrict__ Wxh, const float* __restrict__ Whh,
        const float* __restrict__ bz, const float* __restrict__ br,
        const float* __restrict__ bh,
        float* __restrict__ ws, float* __restrict__ out) {
    const int bid = blockIdx.x;
    const int t = threadIdx.x;
    const int head = dh[0], tail = dt[0];
    const size_t nn = (size_t)NN * NN;
    unsigned* ctr  = (unsigned*)ws + 1024;
    unsigned* done = (unsigned*)ws + 1056;

    // ---------------- chain roles (bids 0..147), then fall through to stream ----
    if (bid < NAGG) {
        // agg partial over rows [bid*64, bid*64+64) + H->out copy (H read once),
        // partial pushed through Cz/Cr (linearity: sum over blocks of partial@C = agg@C).
        __shared__ float e_sh[64];
        __shared__ f32x4 red[4][64];
        __shared__ float agg_sh[CC];
        const int i0 = bid * 64;
        if (t < 64) {
            const int i = i0 + t;
            float e = 0.5f * E[(size_t)head * NN + i];
            if (head != tail) e += 0.5f * E[(size_t)tail * NN + i];
            if (i == tail) e += 0.5f;
            e_sh[t] = e;
        }
        __syncthreads();
        const int g = t >> 6, c = (t & 63) << 2;
        f32x4 acc = {0.f, 0.f, 0.f, 0.f};
        #pragma unroll
        for (int it = 0; it < 16; ++it) {
            const int r = it * 4 + g;
            const int row = i0 + r;
            const f32x4 hv = *(const f32x4*)(H + (size_t)row * CC + c);
            acc += hv * e_sh[r];
            if (row != head)
                *(f32x4*)(out + nn + (size_t)row * CC + c) = hv;
        }
        red[g][t & 63] = acc;
        __syncthreads();
        if (g == 0) {
            const f32x4 s = red[0][t] + red[1][t] + red[2][t] + red[3][t];
            *(f32x4*)(agg_sh + (t << 2)) = s;
        }
        __syncthreads();
        float pz = 0.f, pr = 0.f;
        #pragma unroll 8
        for (int k = 0; k < CC; ++k) {
            const float a = agg_sh[k];
            pz += a * Cz[(size_t)k * CC + t];
            pr += a * Cr[(size_t)k * CC + t];
        }
        atomicAdd(&ws[ACC_Z + t], pz);
        atomicAdd(&ws[ACC_R + t], pr);
        __syncthreads();
    } else if (bid < CHAIN) {
        // 5 agg-independent matvecs x 4 k-chunks. m: 0=Wxz->Z 1=Whz->Z 2=Wxr->R 3=Whr->R 4=Wxh->XH
        const int mb = bid - NAGG;
        const int m = mb >> 2, q = mb & 3;
        __shared__ float v_sh[64];
        const float* W;
        int dsto;
        switch (m) {
            case 0: W = Wxz; dsto = ACC_Z; break;
            case 1: W = Whz; dsto = ACC_Z; break;
            case 2: W = Wxr; dsto = ACC_R; break;
            case 3: W = Whr; dsto = ACC_R; break;
            default: W = Wxh; dsto = ACC_XH; break;
        }
        if (t < 64) {
            const int k = q * 64 + t;
            v_sh[t] = (m == 1 || m == 3) ? H[(size_t)head * CC + k] : X[k];
        }
        __syncthreads();
        float acc = 0.f;
        #pragma unroll
        for (int kk = 0; kk < 64; ++kk)
            acc += v_sh[kk] * W[(size_t)(q * 64 + kk) * CC + t];
        atomicAdd(&ws[dsto + t], acc);
        __syncthreads();
    }

    // ---------------- work-stealing E-stream (all 2048 blocks) ----------------
    // chunk ck covers f32x4 indices [ck*CHUNK, ck*CHUNK+CHUNK); thread t does 16
    // f32x4 at stride 256. Grab-ahead: next chunk id fetched before processing
    // current, so the hot-atomic latency hides under 64 KB of streaming.
    __shared__ unsigned s_chunk[2];
    if (t == 0) s_chunk[0] = atomicAdd(ctr, 1u);
    __syncthreads();
    unsigned cur = s_chunk[0];
    int par = 1;
    while (cur < NCHUNK) {
        if (t == 0) s_chunk[par] = atomicAdd(ctr, 1u);
        const size_t base = (size_t)cur * CHUNK + t;
        #pragma unroll
        for (int k = 0; k < 16; k += 2) {
            const size_t e0 = (base + (size_t)k * 256) << 2;
            const size_t e1 = (base + (size_t)(k + 1) * 256) << 2;
            const f32x4 a = __builtin_nontemporal_load((const f32x4*)(E + e0));
            const f32x4 b = __builtin_nontemporal_load((const f32x4*)(E + e1));
            {
                f32x4 o = a * 0.5f;
                if ((int)(e0 >> LOG2N) == head) {
                    const int j = (int)(e0 & (NN - 1));
                    if (head != tail) {
                        const f32x4 w = *(const f32x4*)(E + (size_t)tail * NN + j);
                        o += w * 0.5f;
                    }
                    if (tail >= j && tail < j + 4) o[tail - j] += 0.5f;
                }
                *(f32x4*)(out + e0) = o;
            }
            {
                f32x4 o = b * 0.5f;
                if ((int)(e1 >> LOG2N) == head) {
                    const int j = (int)(e1 & (NN - 1));
                    if (head != tail) {
                        const f32x4 w = *(const f32x4*)(E + (size_t)tail * NN + j);
                        o += w * 0.5f;
                    }
                    if (tail >= j && tail < j + 4) o[tail - j] += 0.5f;
                }
                *(f32x4*)(out + e1) = o;
            }
        }
        __syncthreads();            // s_chunk[par] now visible to all
        cur = s_chunk[par];
        par ^= 1;
    }

    // ---------------- last finisher runs the GRU epilogue ----------------
    __shared__ int s_last;
    if (t == 0) {
        const unsigned old = __hip_atomic_fetch_add(done, 1u, __ATOMIC_ACQ_REL,
                                                    __HIP_MEMORY_SCOPE_AGENT);
        s_last = (old == GRID - 1) ? 1 : 0;
    }
    __syncthreads();
    if (s_last) {
        __shared__ float rs_sh[CC];
        const float accR = ws[ACC_R + t];
        const float accZ = ws[ACC_Z + t];
        const float accXH = ws[ACC_XH + t];
        const float h = H[(size_t)head * CC + t];
        const float r = 1.f / (1.f + expf(-(br[t] + accR)));
        rs_sh[t] = h * r;
        __syncthreads();
        float hh = 0.f;
        #pragma unroll 8
        for (int k = 0; k < CC; ++k)
            hh += rs_sh[k] * Whh[(size_t)k * CC + t];
        const float z = 1.f / (1.f + expf(-(bz[t] + accZ)));
        const float ht = tanhf(bh[t] + accXH + hh);
        out[nn + (size_t)head * CC + t] = z * h + (1.f - z) * ht;
    }
}

extern "C" void kernel_launch(void* const* d_in, const int* in_sizes, int n_in,
                              void* d_out, int out_size, void* d_ws, size_t ws_size,
                              hipStream_t stream) {
    const float* X    = (const float*)d_in[0];
    const int*   dh   = (const int*)d_in[1];
    const int*   dt   = (const int*)d_in[2];
    const float* E    = (const float*)d_in[3];
    const float* H    = (const float*)d_in[4];
    const float* Wxz  = (const float*)d_in[5];
    const float* Whz  = (const float*)d_in[6];
    const float* Cz   = (const float*)d_in[7];
    const float* bz   = (const float*)d_in[8];
    const float* Wxr  = (const float*)d_in[9];
    const float* Whr  = (const float*)d_in[10];
    const float* Cr   = (const float*)d_in[11];
    const float* br   = (const float*)d_in[12];
    const float* Wxh  = (const float*)d_in[13];
    const float* Whh  = (const float*)d_in[14];
    const float* bh   = (const float*)d_in[15];
    float* out = (float*)d_out;
    float* ws  = (float*)d_ws;

    hipMemsetAsync(ws, 0, 8192, stream);   // accs + ctr + done
    k1<<<GRID, 256, 0, stream>>>(
        X, E, H, dh, dt, Wxz, Whz, Cz, Wxr, Whr, Cr, Wxh, Whh,
        bz, br, bh, ws, out);
}

// Round 9
// 110.462 us; speedup vs baseline: 1.9354x; 1.9354x over previous
//
#include <hip/hip_runtime.h>
#include <math.h>

#define NN 8192
#define CC 256
#define LOG2N 13

typedef float f32x4 __attribute__((ext_vector_type(4)));

// ---------------- ws layout (floats) ----------------
// aggP : [128][256]  offset 0      (agg partials per 64-row chunk; slot-written, no memset)
// mvP  : [20][256]   offset 32768  (m*4+q; m: 0=Wxz->Z 1=Whz->Z 2=Wxr->R 3=Whr->R 4=Wxh->XH)
#define WS_AGGP 0
#define WS_MVP  32768

#define NAGG 128
#define NMV  20

// A: one kernel, two independent block roles (no cross-block deps, no sync).
//  - blocks [0,128): agg partial over rows [b*64, b*64+64) with H->out copy fused
//    (H read exactly once); partial -> aggP[b].
//  - blocks [128,148): the 5 agg-independent matvecs x 4 k-chunks -> mvP slots.
__global__ void __launch_bounds__(256) kA(
        const float* __restrict__ X, const float* __restrict__ E,
        const float* __restrict__ H,
        const int* __restrict__ dh, const int* __restrict__ dt,
        const float* __restrict__ Wxz, const float* __restrict__ Whz,
        const float* __restrict__ Wxr, const float* __restrict__ Whr,
        const float* __restrict__ Wxh,
        float* __restrict__ ws, float* __restrict__ out) {
    const int bid = blockIdx.x;
    const int t = threadIdx.x;
    const int head = dh[0], tail = dt[0];
    const size_t nn = (size_t)NN * NN;
    float* aggP = ws + WS_AGGP;
    float* mvP  = ws + WS_MVP;

    if (bid < NAGG) {
        __shared__ float e_sh[64];
        __shared__ f32x4 red[4][64];
        const int i0 = bid * 64;
        if (t < 64) {
            const int i = i0 + t;
            float e = 0.5f * E[(size_t)head * NN + i];
            if (head != tail) e += 0.5f * E[(size_t)tail * NN + i];
            if (i == tail) e += 0.5f;
            e_sh[t] = e;
        }
        __syncthreads();
        const int g = t >> 6, c = (t & 63) << 2;
        f32x4 acc = {0.f, 0.f, 0.f, 0.f};
        #pragma unroll
        for (int it = 0; it < 16; ++it) {
            const int r = it * 4 + g;
            const int row = i0 + r;
            const f32x4 hv = *(const f32x4*)(H + (size_t)row * CC + c);
            acc += hv * e_sh[r];
            if (row != head)
                *(f32x4*)(out + nn + (size_t)row * CC + c) = hv;  // fused H copy
        }
        red[g][t & 63] = acc;
        __syncthreads();
        if (g == 0) {
            const f32x4 s = red[0][t] + red[1][t] + red[2][t] + red[3][t];
            *(f32x4*)(aggP + bid * CC + (t << 2)) = s;
        }
        return;
    }

    // mv role
    {
        const int mb = bid - NAGG;
        const int m = mb >> 2, q = mb & 3;
        __shared__ float v_sh[64];
        const float* W;
        switch (m) {
            case 0: W = Wxz; break; case 1: W = Whz; break;
            case 2: W = Wxr; break; case 3: W = Whr; break;
            default: W = Wxh; break;
        }
        if (t < 64) {
            const int k = q * 64 + t;
            v_sh[t] = (m == 1 || m == 3) ? H[(size_t)head * CC + k] : X[k];
        }
        __syncthreads();
        float acc = 0.f;
        #pragma unroll
        for (int kk = 0; kk < 64; ++kk)
            acc += v_sh[kk] * W[(size_t)(q * 64 + kk) * CC + t];
        mvP[mb * CC + t] = acc;
    }
}

// B: pure-E streamer (R4-proven 2-deep pattern) + full GRU epilogue in block 0.
// Epilogue (~900 KB of L2/LLC-resident reads, ~10 us) hides under ~88 us of streaming.
__global__ void __launch_bounds__(256) kB(
        const float* __restrict__ E, const float* __restrict__ H,
        const int* __restrict__ dh, const int* __restrict__ dt,
        const float* __restrict__ Cz, const float* __restrict__ Cr,
        const float* __restrict__ Whh,
        const float* __restrict__ bz, const float* __restrict__ br,
        const float* __restrict__ bh,
        const float* __restrict__ ws, float* __restrict__ out) {
    const int head = dh[0], tail = dt[0];
    const size_t nn = (size_t)NN * NN;
    const float* aggP = ws + WS_AGGP;
    const float* mvP  = ws + WS_MVP;

    if (blockIdx.x == 0) {
        __shared__ float agg_sh[CC];
        __shared__ float rs_sh[CC];
        const int t = threadIdx.x;
        // reduce agg partials (coalesced: consecutive t -> consecutive addr)
        float a = 0.f;
        #pragma unroll 8
        for (int b = 0; b < NAGG; ++b) a += aggP[b * CC + t];
        agg_sh[t] = a;
        __syncthreads();
        // conv matvecs on agg
        float pz = 0.f, pr = 0.f;
        #pragma unroll 8
        for (int k = 0; k < CC; ++k) {
            const float av = agg_sh[k];
            pz += av * Cz[(size_t)k * CC + t];
            pr += av * Cr[(size_t)k * CC + t];
        }
        // mv slot reduce
        float sz = bz[t] + pz, sr = br[t] + pr, sxh = 0.f;
        #pragma unroll
        for (int p = 0; p < 8; ++p)   sz += mvP[p * CC + t];
        #pragma unroll
        for (int p = 8; p < 16; ++p)  sr += mvP[p * CC + t];
        #pragma unroll
        for (int p = 16; p < 20; ++p) sxh += mvP[p * CC + t];
        const float h = H[(size_t)head * CC + t];
        const float r = 1.f / (1.f + expf(-sr));
        rs_sh[t] = h * r;
        __syncthreads();
        float hh = 0.f;
        #pragma unroll 16
        for (int k = 0; k < CC; ++k)
            hh += rs_sh[k] * Whh[(size_t)k * CC + t];
        const float z = 1.f / (1.f + expf(-sz));
        const float ht = tanhf(bh[t] + sxh + hh);
        out[nn + (size_t)head * CC + t] = z * h + (1.f - z) * ht;
        return;
    }

    // streamers: blocks 1..2048, R4 loop shape, pure E
    const size_t total4 = nn >> 2;                 // 16,777,216
    const size_t step = (size_t)2048 * 256;        // 524,288
    for (size_t idx = (size_t)(blockIdx.x - 1) * 256 + threadIdx.x;
         idx < total4; idx += 2 * step) {
        const size_t idx2 = idx + step;
        const bool ok2 = idx2 < total4;
        const size_t e0 = idx << 2;
        const f32x4 a = __builtin_nontemporal_load((const f32x4*)(E + e0));
        f32x4 b = {0.f, 0.f, 0.f, 0.f};
        if (ok2) b = __builtin_nontemporal_load((const f32x4*)(E + (idx2 << 2)));
        {
            f32x4 o = a * 0.5f;
            if ((int)(e0 >> LOG2N) == head) {
                const int j = (int)(e0 & (NN - 1));
                if (head != tail) {
                    const f32x4 w = *(const f32x4*)(E + (size_t)tail * NN + j);
                    o += w * 0.5f;
                }
                if (tail >= j && tail < j + 4) o[tail - j] += 0.5f;
            }
            *(f32x4*)(out + e0) = o;
        }
        if (ok2) {
            const size_t e1 = idx2 << 2;
            f32x4 o = b * 0.5f;
            if ((int)(e1 >> LOG2N) == head) {
                const int j = (int)(e1 & (NN - 1));
                if (head != tail) {
                    const f32x4 w = *(const f32x4*)(E + (size_t)tail * NN + j);
                    o += w * 0.5f;
                }
                if (tail >= j && tail < j + 4) o[tail - j] += 0.5f;
            }
            *(f32x4*)(out + e1) = o;
        }
    }
}

extern "C" void kernel_launch(void* const* d_in, const int* in_sizes, int n_in,
                              void* d_out, int out_size, void* d_ws, size_t ws_size,
                              hipStream_t stream) {
    const float* X    = (const float*)d_in[0];
    const int*   dh   = (const int*)d_in[1];
    const int*   dt   = (const int*)d_in[2];
    const float* E    = (const float*)d_in[3];
    const float* H    = (const float*)d_in[4];
    const float* Wxz  = (const float*)d_in[5];
    const float* Whz  = (const float*)d_in[6];
    const float* Cz   = (const float*)d_in[7];
    const float* bz   = (const float*)d_in[8];
    const float* Wxr  = (const float*)d_in[9];
    const float* Whr  = (const float*)d_in[10];
    const float* Cr   = (const float*)d_in[11];
    const float* br   = (const float*)d_in[12];
    const float* Wxh  = (const float*)d_in[13];
    const float* Whh  = (const float*)d_in[14];
    const float* bh   = (const float*)d_in[15];
    float* out = (float*)d_out;
    float* ws  = (float*)d_ws;

    kA<<<NAGG + NMV, 256, 0, stream>>>(X, E, H, dh, dt, Wxz, Whz, Wxr, Whr, Wxh, ws, out);
    kB<<<2049, 256, 0, stream>>>(E, H, dh, dt, Cz, Cr, Whh, bz, br, bh, ws, out);
}